// Round 16
// baseline (1214.110 us; speedup 1.0000x reference)
//
#include <hip/hip_runtime.h>
#include <math.h>

// Problem constants
// H=256, D_IN=22, T=384, 4H=1024, N_R=N_L=384, H1=1024, H2=512, H3=1024, RRI=2

typedef _Float16 half2_t __attribute__((ext_vector_type(2)));

__device__ __forceinline__ float fast_sig(float x) {
    float e = __expf(-x);
    return __builtin_amdgcn_rcpf(1.f + e);
}
__device__ __forceinline__ float fast_tanh(float x) {
    x = fminf(fmaxf(x, -30.f), 30.f);
    float e = __expf(2.f * x);
    return (e - 1.f) * __builtin_amdgcn_rcpf(e + 1.f);
}

// ---------------------------------------------------------------------------
// prep
// ---------------------------------------------------------------------------
__global__ __launch_bounds__(256) void prep_kernel(
    const float* __restrict__ bih0, const float* __restrict__ bhh0,
    const float* __restrict__ bih1, const float* __restrict__ bhh1,
    const float* __restrict__ W3,   const float* __restrict__ Wout,
    float* __restrict__ b0sum, float* __restrict__ b1sum,
    float* __restrict__ W3sum, float* __restrict__ woutT)
{
    int idx = blockIdx.x * 256 + threadIdx.x;
    int stride = gridDim.x * 256;
    if (idx < 2048) {
        b0sum[idx] = bih0[idx] + bhh0[idx];
        b1sum[idx] = bih1[idx] + bhh1[idx];
        woutT[idx] = Wout[(idx & 1) * 1024 + (idx >> 1)];
    }
    for (int i = idx; i < 1024 * 512; i += stride) {
        int n = i >> 9, k = i & 511;
        W3sum[i] = W3[n * 1024 + k] + W3[n * 1024 + 512 + k];
    }
}

// ---------------------------------------------------------------------------
// proj0
// ---------------------------------------------------------------------------
__global__ __launch_bounds__(256) void proj0_kernel(
    const float* __restrict__ v_r, const float* __restrict__ v_l,
    const float* __restrict__ Wih0, const float* __restrict__ b0sum,
    float* __restrict__ pre0)
{
    int t = blockIdx.x;
    int sd = blockIdx.y;            // seq*2 + dir
    int seq = sd >> 1, dir = sd & 1;
    const float* x = (seq ? v_l : v_r) + t * 22;
    __shared__ float sx[22];
    if (threadIdx.x < 22) sx[threadIdx.x] = x[threadIdx.x];
    __syncthreads();
#pragma unroll
    for (int q = 0; q < 4; ++q) {
        int o = q * 256 + threadIdx.x;
        const float* wr = Wih0 + (size_t)(dir * 1024 + o) * 22;
        float acc = b0sum[dir * 1024 + o];
#pragma unroll
        for (int d = 0; d < 22; ++d) acc += sx[d] * wr[d];
        pre0[((size_t)sd * 384 + t) * 1024 + o] = acc;
    }
}

// ---------------------------------------------------------------------------
// LSTM recurrence, v16 = v15 + __launch_bounds__(512, 2).
// R15 post-mortem: VGPR_Count=52 — without a min-waves hint the allocator
// targeted the 8-waves/SIMD tier (64-VGPR budget) and spilled ALL 64 pinned
// weight floats to scratch (~2300 cyc/step reload; step 2890). R7-R10
// showed __launch_bounds__(512,2) raises the tier to ~128 VGPRs; they still
// spilled because they pinned 128 floats. v16 = the untested combination:
// 64 pinned floats (demand ~100) + the ',2' hint (budget ~128) -> zero
// spill for the first time.
// Topology (R15, passed): 4 WGs/chain, grid 32, all 512 KB chain weights
// register-resident across the 4 WGs; v10 tagged-publish protocol, 2
// barriers/step, bounded spin; hh4 segment stride 5 float4 (conflict-free);
// all-lane redundant bit-identical c/h (R8).
// ---------------------------------------------------------------------------
__global__ __launch_bounds__(512, 2) void lstm_rec_kernel(
    const float* __restrict__ Whh,   // [2][1024][256] fp32
    const float* __restrict__ pre,   // layer0: [(seq*2+dir)][384][1024]; layer1: [(seq*384+t)][2][1024]
    float* __restrict__ out,         // [2][384][512]  (cols: dir*256 + j)
    unsigned long long* pub,         // [4 chains][2 parity][128]
    int layer)
{
    const int b = blockIdx.x;
    const int chain = b & 7;                 // XCD id under %8 round-robin
    const int w = b >> 3;                    // 0..3
    if (chain >= 4) return;
    const int seq = chain >> 1, dir = chain & 1;
    const int tid = threadIdx.x;
    const int ks = tid & 7;                  // 32-wide k-slice
    const int jloc = tid >> 3;               // 0..63
    const int jj = (w << 6) + jloc;          // own h index

    // h in LDS: 8 segments (one per k-slice) of 16 half2, stride 5 float4
    // (4 used + 1 pad) -> the 8 broadcast b128 reads tile all 32 banks.
    __shared__ __align__(16) float4 hh4[2][40];

    // 64 pinned register weights: wA[g*16+q] = half2 (k=32ks+2q) of row g*256+jj.
    float wA[64];
#pragma unroll
    for (int g = 0; g < 4; ++g) {
        const float* wr = Whh + (((size_t)(dir * 1024 + g * 256 + jj)) << 8) + (ks << 5);
#pragma unroll
        for (int q = 0; q < 16; ++q) {
            float2 v = *(const float2*)(wr + 2 * q);
            half2_t h2; h2.x = (_Float16)v.x; h2.y = (_Float16)v.y;
            wA[g * 16 + q] = __builtin_bit_cast(float, h2);
        }
    }
#pragma unroll
    for (int q = 0; q < 64; ++q) asm volatile("" : "+v"(wA[q]));

    if (tid < 320) ((float*)hh4)[tid] = 0.f;    // both parities zeroed
    float cstate = 0.f;                      // redundant in 8 lanes, bit-identical
    __syncthreads();

    for (int s = 0; s < 384; ++s) {
        const int t = dir ? (383 - s) : s;
        const float* pre_t = (layer == 0)
            ? pre + ((size_t)(seq * 2 + dir) * 384 + t) * 1024
            : pre + (((size_t)(seq * 384 + t)) * 2 + dir) * 1024;
        float pv = (ks < 4) ? pre_t[(ks << 8) + jj] : 0.f;  // drains under fdot

        const int par = s & 1, pn = par ^ 1;
        // ---- Phase 1: poll 3 peers' h_{s-1} (tag s) ----
        if (s > 0 && ks >= 6) {
            int cid = (jloc << 1) | (ks - 6);       // 0..127
            if (cid < 96) {
                int peer = cid >> 5;                // 0..2
                int p = cid & 31;
                int wp = (w + 1 + peer) & 3;
                int P = (wp << 5) + p;              // global pair index
                const unsigned long long* src =
                    &pub[((size_t)chain * 2 + par) * 128 + P];
                const unsigned expect = (unsigned)s;
                unsigned long long v =
                    __hip_atomic_load(src, __ATOMIC_RELAXED, __HIP_MEMORY_SCOPE_AGENT);
                if ((unsigned)(v >> 32) != expect) {
                    for (int it = 0; it < 65536; ++it) {
                        __builtin_amdgcn_s_sleep(1);
                        v = __hip_atomic_load(src, __ATOMIC_RELAXED, __HIP_MEMORY_SCOPE_AGENT);
                        if ((unsigned)(v >> 32) == expect) break;
                    }
                }
                ((half2_t*)&hh4[par][0])[(P >> 4) * 20 + (P & 15)] =
                    __builtin_bit_cast(half2_t, (unsigned)v);
            }
        }
        __syncthreads();                     // hh4[par] = complete h_{s-1}

        // ---- Phase 2: fdot over own k-slice, all weights in registers ----
        const float4* hb = &hh4[par][ks * 5];
        float4 hl0 = hb[0], hl1 = hb[1], hl2 = hb[2], hl3 = hb[3];
        const float4 hls[4] = {hl0, hl1, hl2, hl3};
        float a0 = 0.f, a1 = 0.f, a2 = 0.f, a3 = 0.f;
#pragma unroll
        for (int m = 0; m < 4; ++m) {
            const float he[4] = {hls[m].x, hls[m].y, hls[m].z, hls[m].w};
#pragma unroll
            for (int e = 0; e < 4; ++e) {
                half2_t hv = __builtin_bit_cast(half2_t, he[e]);
                int q = 4 * m + e;
                a0 = __builtin_amdgcn_fdot2(__builtin_bit_cast(half2_t, wA[q]),      hv, a0, false);
                a1 = __builtin_amdgcn_fdot2(__builtin_bit_cast(half2_t, wA[16 + q]), hv, a1, false);
                a2 = __builtin_amdgcn_fdot2(__builtin_bit_cast(half2_t, wA[32 + q]), hv, a2, false);
                a3 = __builtin_amdgcn_fdot2(__builtin_bit_cast(half2_t, wA[48 + q]), hv, a3, false);
            }
        }
        // Fold pre exactly once (lane ks<4 owns gate ks), butterfly 8 lanes.
        a0 += (ks == 0) ? pv : 0.f;
        a1 += (ks == 1) ? pv : 0.f;
        a2 += (ks == 2) ? pv : 0.f;
        a3 += (ks == 3) ? pv : 0.f;
#pragma unroll
        for (int d = 1; d < 8; d <<= 1) {
            a0 += __shfl_xor(a0, d);
            a1 += __shfl_xor(a1, d);
            a2 += __shfl_xor(a2, d);
            a3 += __shfl_xor(a3, d);
        }

        // All lanes: redundant gate update (bit-identical across 8 k-lanes).
        float iv = fast_sig(a0);
        float fv = fast_sig(a1);
        float gv = fast_tanh(a2);
        float ov = fast_sig(a3);
        cstate = fv * cstate + iv * gv;
        float h = ov * fast_tanh(cstate);

        unsigned hb16 = (unsigned)__builtin_bit_cast(unsigned short, (_Float16)h);
        unsigned nb = (unsigned)__shfl_xor((int)hb16, 8);   // partner jloc^1
        if (ks == 0) {
            ((unsigned short*)&hh4[pn][0])[(jj >> 5) * 40 + (jj & 31)] =
                (unsigned short)hb16;
            if ((jloc & 1) == 0) {
                unsigned payload = (hb16 & 0xffffu) | (nb << 16);
                int P = (w << 5) + (jloc >> 1);
                unsigned long long pk =
                    ((unsigned long long)(unsigned)(s + 1) << 32) | payload;
                __hip_atomic_store(&pub[((size_t)chain * 2 + pn) * 128 + P], pk,
                                   __ATOMIC_RELAXED, __HIP_MEMORY_SCOPE_AGENT);
            }
        }
        if (ks == 1) {
            out[((size_t)seq * 384 + t) * 512 + dir * 256 + jj] = h;
        }
        __syncthreads();                     // hh4[pn] own region complete
    }
}

// ---------------------------------------------------------------------------
// Generic NT GEMM: C[M][N] = act(scale * A[M][K] @ W[N][K]^T + bias[N])
// ---------------------------------------------------------------------------
__global__ __launch_bounds__(256) void gemm_nt_kernel(
    const float* __restrict__ A, const float* __restrict__ W,
    const float* __restrict__ bias, float* __restrict__ C,
    int M, int N, int K, float scale, int do_relu)
{
    __shared__ float As[32][68];
    __shared__ float Ws[32][68];
    const int tid = threadIdx.x;
    const int n0 = blockIdx.x * 64, m0 = blockIdx.y * 64;
    const int lr = tid >> 2;
    const int lk = (tid & 3) * 8;
    const int tm = tid >> 4, tn = tid & 15;
    float acc[4][4];
#pragma unroll
    for (int i = 0; i < 4; ++i)
#pragma unroll
        for (int j = 0; j < 4; ++j) acc[i][j] = 0.f;

    for (int kc = 0; kc < K; kc += 32) {
        float4 a0 = *(const float4*)(A + (size_t)(m0 + lr) * K + kc + lk);
        float4 a1 = *(const float4*)(A + (size_t)(m0 + lr) * K + kc + lk + 4);
        float4 w0 = *(const float4*)(W + (size_t)(n0 + lr) * K + kc + lk);
        float4 w1 = *(const float4*)(W + (size_t)(n0 + lr) * K + kc + lk + 4);
        __syncthreads();
        As[lk + 0][lr] = a0.x; As[lk + 1][lr] = a0.y; As[lk + 2][lr] = a0.z; As[lk + 3][lr] = a0.w;
        As[lk + 4][lr] = a1.x; As[lk + 5][lr] = a1.y; As[lk + 6][lr] = a1.z; As[lk + 7][lr] = a1.w;
        Ws[lk + 0][lr] = w0.x; Ws[lk + 1][lr] = w0.y; Ws[lk + 2][lr] = w0.z; Ws[lk + 3][lr] = w0.w;
        Ws[lk + 4][lr] = w1.x; Ws[lk + 5][lr] = w1.y; Ws[lk + 6][lr] = w1.z; Ws[lk + 7][lr] = w1.w;
        __syncthreads();
#pragma unroll
        for (int kk = 0; kk < 32; ++kk) {
            float4 av = *(const float4*)&As[kk][tm * 4];
            float4 wv = *(const float4*)&Ws[kk][tn * 4];
            acc[0][0] += av.x * wv.x; acc[0][1] += av.x * wv.y; acc[0][2] += av.x * wv.z; acc[0][3] += av.x * wv.w;
            acc[1][0] += av.y * wv.x; acc[1][1] += av.y * wv.y; acc[1][2] += av.y * wv.z; acc[1][3] += av.y * wv.w;
            acc[2][0] += av.z * wv.x; acc[2][1] += av.z * wv.y; acc[2][2] += av.z * wv.z; acc[2][3] += av.z * wv.w;
            acc[3][0] += av.w * wv.x; acc[3][1] += av.w * wv.y; acc[3][2] += av.w * wv.z; acc[3][3] += av.w * wv.w;
        }
    }
    float4 bv = make_float4(0.f, 0.f, 0.f, 0.f);
    if (bias) bv = *(const float4*)(bias + n0 + tn * 4);
#pragma unroll
    for (int i = 0; i < 4; ++i) {
        int m = m0 + tm * 4 + i;
        float4 v;
        v.x = scale * acc[i][0] + bv.x;
        v.y = scale * acc[i][1] + bv.y;
        v.z = scale * acc[i][2] + bv.z;
        v.w = scale * acc[i][3] + bv.w;
        if (do_relu) {
            v.x = fmaxf(v.x, 0.f); v.y = fmaxf(v.y, 0.f);
            v.z = fmaxf(v.z, 0.f); v.w = fmaxf(v.w, 0.f);
        }
        *(float4*)(C + (size_t)m * N + n0 + tn * 4) = v;
    }
}

// ---------------------------------------------------------------------------
// pairwise: out[i][j][:] = log_softmax( sum_c relu(ur'[i][c]+ul[j][c]) * woutT[c][:] + bout )
// Stride 132 + row remap -> <=2-way conflicts (R7 fix).
// ---------------------------------------------------------------------------
__global__ __launch_bounds__(256) void pairwise_kernel(
    const float* __restrict__ u,      // [768][1024]
    const float* __restrict__ woutT,  // [1024][2]
    const float* __restrict__ bout,   // [2]
    float* __restrict__ out)          // [384][384][2]
{
    __shared__ float Ur[32][132];
    __shared__ float Ul[32][132];
    __shared__ float Wo[256];
    const int tid = threadIdx.x;
    const int j0 = blockIdx.x * 32, i0 = blockIdx.y * 32;
    const int ii = tid >> 4, jj = tid & 15;
    const int il0 = ii, il1 = ii + 16;
    const int jl0 = jj, jl1 = jj + 16;
    float acc000 = 0.f, acc001 = 0.f, acc010 = 0.f, acc011 = 0.f;
    float acc100 = 0.f, acc101 = 0.f, acc110 = 0.f, acc111 = 0.f;
    const int lrw = tid >> 3;
    const int lcb = (tid & 7) * 16;

    for (int cc = 0; cc < 1024; cc += 128) {
        __syncthreads();
#pragma unroll
        for (int q = 0; q < 4; ++q) {
            *(float4*)&Ur[lrw][lcb + 4 * q] =
                *(const float4*)(u + (size_t)(i0 + lrw) * 1024 + cc + lcb + 4 * q);
            *(float4*)&Ul[lrw][lcb + 4 * q] =
                *(const float4*)(u + (size_t)(384 + j0 + lrw) * 1024 + cc + lcb + 4 * q);
        }
        if (tid < 128)
            *(float2*)&Wo[tid * 2] = *(const float2*)(woutT + (size_t)(cc + tid) * 2);
        __syncthreads();

        for (int c = 0; c < 128; c += 4) {
            float4 a0  = *(const float4*)&Ur[il0][c];
            float4 a1  = *(const float4*)&Ur[il1][c];
            float4 b0v = *(const float4*)&Ul[jl0][c];
            float4 b1v = *(const float4*)&Ul[jl1][c];
            float4 wA4 = *(const float4*)&Wo[c * 2];
            float4 wB4 = *(const float4*)&Wo[c * 2 + 4];
#define PW_STEP(AX, W0, W1)                                   \
            { float rr;                                       \
              rr = fmaxf(a0.AX + b0v.AX, 0.f); acc000 += rr*(W0); acc001 += rr*(W1); \
              rr = fmaxf(a0.AX + b1v.AX, 0.f); acc010 += rr*(W0); acc011 += rr*(W1); \
              rr = fmaxf(a1.AX + b0v.AX, 0.f); acc100 += rr*(W0); acc101 += rr*(W1); \
              rr = fmaxf(a1.AX + b1v.AX, 0.f); acc110 += rr*(W0); acc111 += rr*(W1); }
            PW_STEP(x, wA4.x, wA4.y)
            PW_STEP(y, wA4.z, wA4.w)
            PW_STEP(z, wB4.x, wB4.y)
            PW_STEP(w, wB4.z, wB4.w)
#undef PW_STEP
        }
    }
    float2 bo = *(const float2*)bout;
    float pa[2][2][2] = {{{acc000, acc001}, {acc010, acc011}},
                         {{acc100, acc101}, {acc110, acc111}}};
#pragma unroll
    for (int pi = 0; pi < 2; ++pi)
#pragma unroll
        for (int pj = 0; pj < 2; ++pj) {
            float l0 = pa[pi][pj][0] + bo.x;
            float l1 = pa[pi][pj][1] + bo.y;
            float m = fmaxf(l0, l1);
            float lse = m + logf(expf(l0 - m) + expf(l1 - m));
            int ig = i0 + ii + 16 * pi;
            int jg = j0 + jj + 16 * pj;
            float2 o2; o2.x = l0 - lse; o2.y = l1 - lse;
            *(float2*)(out + ((size_t)ig * 384 + jg) * 2) = o2;
        }
}

// ---------------------------------------------------------------------------
extern "C" void kernel_launch(void* const* d_in, const int* in_sizes, int n_in,
                              void* d_out, int out_size, void* d_ws, size_t ws_size,
                              hipStream_t stream)
{
    const float* v_r  = (const float*)d_in[0];
    const float* v_l  = (const float*)d_in[1];
    const float* Wih0 = (const float*)d_in[2];
    const float* Whh0 = (const float*)d_in[3];
    const float* bih0 = (const float*)d_in[4];
    const float* bhh0 = (const float*)d_in[5];
    const float* Wih1 = (const float*)d_in[6];
    const float* Whh1 = (const float*)d_in[7];
    const float* bih1 = (const float*)d_in[8];
    const float* bhh1 = (const float*)d_in[9];
    const float* W1   = (const float*)d_in[10];
    const float* b1   = (const float*)d_in[11];
    const float* W2   = (const float*)d_in[12];
    const float* b2   = (const float*)d_in[13];
    const float* W3   = (const float*)d_in[14];
    const float* b3   = (const float*)d_in[15];
    const float* Wout = (const float*)d_in[16];
    const float* bout = (const float*)d_in[17];
    float* out = (float*)d_out;

    float* ws = (float*)d_ws;
    size_t off = 0;
    float* b0sum = ws + off; off += 2048;
    float* b1sum = ws + off; off += 2048;
    float* W3sum = ws + off; off += 1024 * 512;
    float* woutT = ws + off; off += 2048;
    float* pre0  = ws + off; off += (size_t)4 * 384 * 1024;
    float* out0  = ws + off; off += (size_t)2 * 384 * 512;
    float* pre1  = ws + off; off += (size_t)768 * 2048;
    float* out1  = ws + off; off += (size_t)2 * 384 * 512;
    float* h1    = ws + off; off += (size_t)768 * 1024;
    float* h2    = ws + off; off += (size_t)768 * 512;
    float* u     = ws + off; off += (size_t)768 * 1024;
    unsigned long long* pub0 = (unsigned long long*)(ws + off); off += 4 * 2 * 128 * 2;
    unsigned long long* pub1 = (unsigned long long*)(ws + off); off += 4 * 2 * 128 * 2;

    prep_kernel<<<512, 256, 0, stream>>>(bih0, bhh0, bih1, bhh1, W3, Wout,
                                         b0sum, b1sum, W3sum, woutT);
    proj0_kernel<<<dim3(384, 4), 256, 0, stream>>>(v_r, v_l, Wih0, b0sum, pre0);
    lstm_rec_kernel<<<32, 512, 0, stream>>>(Whh0, pre0, out0, pub0, 0);
    gemm_nt_kernel<<<dim3(2048 / 64, 768 / 64), 256, 0, stream>>>(
        out0, Wih1, b1sum, pre1, 768, 2048, 512, 1.f, 0);
    lstm_rec_kernel<<<32, 512, 0, stream>>>(Whh1, pre1, out1, pub1, 1);
    gemm_nt_kernel<<<dim3(1024 / 64, 768 / 64), 256, 0, stream>>>(
        out1, W1, b1, h1, 768, 1024, 512, 1.f, 1);
    gemm_nt_kernel<<<dim3(512 / 64, 768 / 64), 256, 0, stream>>>(
        h1, W2, b2, h2, 768, 512, 1024, 1.f, 1);
    gemm_nt_kernel<<<dim3(1024 / 64, 384 / 64), 256, 0, stream>>>(
        h2, W3sum, b3, u, 384, 1024, 512, 0.5f, 0);
    gemm_nt_kernel<<<dim3(1024 / 64, 384 / 64), 256, 0, stream>>>(
        h2 + (size_t)384 * 512, W3sum, nullptr, u + (size_t)384 * 1024, 384, 1024, 512, 0.5f, 0);
    pairwise_kernel<<<dim3(12, 12), 256, 0, stream>>>(u, woutT, bout, out);
}

// Round 17
// 1213.792 us; speedup vs baseline: 1.0003x; 1.0003x over previous
//
#include <hip/hip_runtime.h>
#include <math.h>

// Problem constants
// H=256, D_IN=22, T=384, 4H=1024, N_R=N_L=384, H1=1024, H2=512, H3=1024, RRI=2

typedef _Float16 half2_t __attribute__((ext_vector_type(2)));

__device__ __forceinline__ float fast_sig(float x) {
    float e = __expf(-x);
    return __builtin_amdgcn_rcpf(1.f + e);
}
__device__ __forceinline__ float fast_tanh(float x) {
    x = fminf(fmaxf(x, -30.f), 30.f);
    float e = __expf(2.f * x);
    return (e - 1.f) * __builtin_amdgcn_rcpf(e + 1.f);
}

// ---------------------------------------------------------------------------
// prep
// ---------------------------------------------------------------------------
__global__ __launch_bounds__(256) void prep_kernel(
    const float* __restrict__ bih0, const float* __restrict__ bhh0,
    const float* __restrict__ bih1, const float* __restrict__ bhh1,
    const float* __restrict__ W3,   const float* __restrict__ Wout,
    float* __restrict__ b0sum, float* __restrict__ b1sum,
    float* __restrict__ W3sum, float* __restrict__ woutT)
{
    int idx = blockIdx.x * 256 + threadIdx.x;
    int stride = gridDim.x * 256;
    if (idx < 2048) {
        b0sum[idx] = bih0[idx] + bhh0[idx];
        b1sum[idx] = bih1[idx] + bhh1[idx];
        woutT[idx] = Wout[(idx & 1) * 1024 + (idx >> 1)];
    }
    for (int i = idx; i < 1024 * 512; i += stride) {
        int n = i >> 9, k = i & 511;
        W3sum[i] = W3[n * 1024 + k] + W3[n * 1024 + 512 + k];
    }
}

// ---------------------------------------------------------------------------
// proj0
// ---------------------------------------------------------------------------
__global__ __launch_bounds__(256) void proj0_kernel(
    const float* __restrict__ v_r, const float* __restrict__ v_l,
    const float* __restrict__ Wih0, const float* __restrict__ b0sum,
    float* __restrict__ pre0)
{
    int t = blockIdx.x;
    int sd = blockIdx.y;            // seq*2 + dir
    int seq = sd >> 1, dir = sd & 1;
    const float* x = (seq ? v_l : v_r) + t * 22;
    __shared__ float sx[22];
    if (threadIdx.x < 22) sx[threadIdx.x] = x[threadIdx.x];
    __syncthreads();
#pragma unroll
    for (int q = 0; q < 4; ++q) {
        int o = q * 256 + threadIdx.x;
        const float* wr = Wih0 + (size_t)(dir * 1024 + o) * 22;
        float acc = b0sum[dir * 1024 + o];
#pragma unroll
        for (int d = 0; d < 22; ++d) acc += sx[d] * wr[d];
        pre0[((size_t)sd * 384 + t) * 1024 + o] = acc;
    }
}

// ---------------------------------------------------------------------------
// LSTM recurrence, v17: 8 WGs/chain — 32 pinned weight floats/thread fits
// even the allocator's max-occupancy (64-VGPR) tier. FIVE rounds (R1, R2,
// R11, R12, R16) proved the allocator spills anything beyond its chosen
// tier and ignores every occupancy hint. v17 sidesteps the fight: demand
// ~64 VGPRs total -> no spill BY DESIGN; all 512 KB chain weights live in
// registers across 8 WGs.
// Grid 64, block 512: chain=b&7 (>=4 exit), w=b>>3 in [0,8); chain's 8 WGs
// = blocks {c,c+8,..,c+56} -> all on XCD c (%8 round-robin). 32 active CUs.
// Thread (jloc=tid>>4 in [0,32), ks=tid&15): owns 4 gate rows for
// jj = w*32+jloc over k in [16ks,16ks+16) -> 4x8 half2 = 32 pinned floats.
// Step s (R15-proven protocol, 8 parties):
//   [ks>=12, cid<112: poll 7 peers' tag-s pairs -> hh[par] remote]
//   [barrier] [fdot 32/thread, h via 2x ds_read_b128 (seg stride 12 floats:
//    16B-aligned, bank bases 2-way = free)] [fold pre (lane ks<4 owns gate
//    ks); butterfly d=1,2,4,8 -> all 16 lanes hold 4 gate sums; redundant
//    bit-identical c/h (R8)]
//   [ks==0: hh[pn] own h + (jloc even) publish pair tag s+1; ks==1: out]
//   [barrier]
// Poll(tag s) precedes publish(tag s+1) in program order; tag-s publishes
// happened the previous iteration -> deadlock-free by induction (R15).
// Bounded s_sleep spin (R4) -> worst case absmax failure, never a hang.
// ---------------------------------------------------------------------------
__global__ __launch_bounds__(512, 2) void lstm_rec_kernel(
    const float* __restrict__ Whh,   // [2][1024][256] fp32
    const float* __restrict__ pre,   // layer0: [(seq*2+dir)][384][1024]; layer1: [(seq*384+t)][2][1024]
    float* __restrict__ out,         // [2][384][512]  (cols: dir*256 + j)
    unsigned long long* pub,         // [4 chains][2 parity][128]
    int layer)
{
    const int b = blockIdx.x;
    const int chain = b & 7;                 // XCD id under %8 round-robin
    const int w = b >> 3;                    // 0..7
    if (chain >= 4) return;
    const int seq = chain >> 1, dir = chain & 1;
    const int tid = threadIdx.x;
    const int ks = tid & 15;                 // 16-wide k-slice
    const int jloc = tid >> 4;               // 0..31
    const int jj = (w << 5) + jloc;          // own h index in [0,256)

    // h in LDS: per parity, 16 segments (one per k-slice) of 8 floats
    // (8 half2 = 16 h values), stride 12 floats (48 B -> 16B-aligned b128;
    // segment bank bases repeat after 8 -> 2-way aliasing = free).
    __shared__ __align__(16) float hhf[2][192];

    // 32 pinned register weights: wA[g*8+q] = half2 (k=16ks+2q) of row g*256+jj.
    float wA[32];
#pragma unroll
    for (int g = 0; g < 4; ++g) {
        const float* wr = Whh + (((size_t)(dir * 1024 + g * 256 + jj)) << 8) + (ks << 4);
#pragma unroll
        for (int q = 0; q < 8; ++q) {
            float2 v = *(const float2*)(wr + 2 * q);
            half2_t h2; h2.x = (_Float16)v.x; h2.y = (_Float16)v.y;
            wA[g * 8 + q] = __builtin_bit_cast(float, h2);
        }
    }
#pragma unroll
    for (int q = 0; q < 32; ++q) asm volatile("" : "+v"(wA[q]));

    if (tid < 384) ((float*)hhf)[tid] = 0.f;   // both parities zeroed
    float cstate = 0.f;                      // redundant in 16 lanes, bit-identical
    __syncthreads();

    for (int s = 0; s < 384; ++s) {
        const int t = dir ? (383 - s) : s;
        const float* pre_t = (layer == 0)
            ? pre + ((size_t)(seq * 2 + dir) * 384 + t) * 1024
            : pre + (((size_t)(seq * 384 + t)) * 2 + dir) * 1024;
        float pv = (ks < 4) ? pre_t[(ks << 8) + jj] : 0.f;  // drains under fdot

        const int par = s & 1, pn = par ^ 1;
        // ---- Phase 1: poll 7 peers' h_{s-1} (tag s) ----
        if (s > 0 && ks >= 12) {
            int cid = (jloc << 2) | (ks - 12);      // 0..127
            if (cid < 112) {
                int peer = cid >> 4;                // 0..6
                int p = cid & 15;
                int wp = (w + 1 + peer) & 7;
                int P = (wp << 4) + p;              // global pair index [0,128)
                const unsigned long long* src =
                    &pub[((size_t)chain * 2 + par) * 128 + P];
                const unsigned expect = (unsigned)s;
                unsigned long long v =
                    __hip_atomic_load(src, __ATOMIC_RELAXED, __HIP_MEMORY_SCOPE_AGENT);
                if ((unsigned)(v >> 32) != expect) {
                    for (int it = 0; it < 65536; ++it) {
                        __builtin_amdgcn_s_sleep(1);
                        v = __hip_atomic_load(src, __ATOMIC_RELAXED, __HIP_MEMORY_SCOPE_AGENT);
                        if ((unsigned)(v >> 32) == expect) break;
                    }
                }
                hhf[par][(P >> 3) * 12 + (P & 7)] = __uint_as_float((unsigned)v);
            }
        }
        __syncthreads();                     // hhf[par] = complete h_{s-1}

        // ---- Phase 2: fdot over own 16-k slice, weights all in registers ----
        const float4* hb = (const float4*)(hhf[par] + ks * 12);
        float4 hA = hb[0], hB = hb[1];
        const float he[8] = {hA.x, hA.y, hA.z, hA.w, hB.x, hB.y, hB.z, hB.w};
        float a0 = 0.f, a1 = 0.f, a2 = 0.f, a3 = 0.f;
#pragma unroll
        for (int q = 0; q < 8; ++q) {
            half2_t hv = __builtin_bit_cast(half2_t, he[q]);
            a0 = __builtin_amdgcn_fdot2(__builtin_bit_cast(half2_t, wA[q]),      hv, a0, false);
            a1 = __builtin_amdgcn_fdot2(__builtin_bit_cast(half2_t, wA[8 + q]),  hv, a1, false);
            a2 = __builtin_amdgcn_fdot2(__builtin_bit_cast(half2_t, wA[16 + q]), hv, a2, false);
            a3 = __builtin_amdgcn_fdot2(__builtin_bit_cast(half2_t, wA[24 + q]), hv, a3, false);
        }
        // Fold pre exactly once (lane ks<4 owns gate ks), butterfly 16 lanes.
        a0 += (ks == 0) ? pv : 0.f;
        a1 += (ks == 1) ? pv : 0.f;
        a2 += (ks == 2) ? pv : 0.f;
        a3 += (ks == 3) ? pv : 0.f;
#pragma unroll
        for (int d = 1; d < 16; d <<= 1) {
            a0 += __shfl_xor(a0, d);
            a1 += __shfl_xor(a1, d);
            a2 += __shfl_xor(a2, d);
            a3 += __shfl_xor(a3, d);
        }

        // All lanes: redundant gate update (bit-identical across 16 k-lanes).
        float iv = fast_sig(a0);
        float fv = fast_sig(a1);
        float gv = fast_tanh(a2);
        float ov = fast_sig(a3);
        cstate = fv * cstate + iv * gv;
        float h = ov * fast_tanh(cstate);

        unsigned hb16 = (unsigned)__builtin_bit_cast(unsigned short, (_Float16)h);
        unsigned nb = (unsigned)__shfl_xor((int)hb16, 16);   // partner jloc^1
        if (ks == 0) {
            // own h into hh[pn]: pair P=jj>>1, segment P>>3, slot P&7, half jj&1
            int fidx = ((jj >> 4) * 12) + ((jj >> 1) & 7);
            ((unsigned short*)hhf[pn])[2 * fidx + (jj & 1)] = (unsigned short)hb16;
            if ((jloc & 1) == 0) {
                unsigned payload = (hb16 & 0xffffu) | (nb << 16);
                int P = (w << 4) + (jloc >> 1);
                unsigned long long pk =
                    ((unsigned long long)(unsigned)(s + 1) << 32) | payload;
                __hip_atomic_store(&pub[((size_t)chain * 2 + pn) * 128 + P], pk,
                                   __ATOMIC_RELAXED, __HIP_MEMORY_SCOPE_AGENT);
            }
        }
        if (ks == 1) {
            out[((size_t)seq * 384 + t) * 512 + dir * 256 + jj] = h;
        }
        __syncthreads();                     // hhf[pn] own region complete
    }
}

// ---------------------------------------------------------------------------
// Generic NT GEMM: C[M][N] = act(scale * A[M][K] @ W[N][K]^T + bias[N])
// ---------------------------------------------------------------------------
__global__ __launch_bounds__(256) void gemm_nt_kernel(
    const float* __restrict__ A, const float* __restrict__ W,
    const float* __restrict__ bias, float* __restrict__ C,
    int M, int N, int K, float scale, int do_relu)
{
    __shared__ float As[32][68];
    __shared__ float Ws[32][68];
    const int tid = threadIdx.x;
    const int n0 = blockIdx.x * 64, m0 = blockIdx.y * 64;
    const int lr = tid >> 2;
    const int lk = (tid & 3) * 8;
    const int tm = tid >> 4, tn = tid & 15;
    float acc[4][4];
#pragma unroll
    for (int i = 0; i < 4; ++i)
#pragma unroll
        for (int j = 0; j < 4; ++j) acc[i][j] = 0.f;

    for (int kc = 0; kc < K; kc += 32) {
        float4 a0 = *(const float4*)(A + (size_t)(m0 + lr) * K + kc + lk);
        float4 a1 = *(const float4*)(A + (size_t)(m0 + lr) * K + kc + lk + 4);
        float4 w0 = *(const float4*)(W + (size_t)(n0 + lr) * K + kc + lk);
        float4 w1 = *(const float4*)(W + (size_t)(n0 + lr) * K + kc + lk + 4);
        __syncthreads();
        As[lk + 0][lr] = a0.x; As[lk + 1][lr] = a0.y; As[lk + 2][lr] = a0.z; As[lk + 3][lr] = a0.w;
        As[lk + 4][lr] = a1.x; As[lk + 5][lr] = a1.y; As[lk + 6][lr] = a1.z; As[lk + 7][lr] = a1.w;
        Ws[lk + 0][lr] = w0.x; Ws[lk + 1][lr] = w0.y; Ws[lk + 2][lr] = w0.z; Ws[lk + 3][lr] = w0.w;
        Ws[lk + 4][lr] = w1.x; Ws[lk + 5][lr] = w1.y; Ws[lk + 6][lr] = w1.z; Ws[lk + 7][lr] = w1.w;
        __syncthreads();
#pragma unroll
        for (int kk = 0; kk < 32; ++kk) {
            float4 av = *(const float4*)&As[kk][tm * 4];
            float4 wv = *(const float4*)&Ws[kk][tn * 4];
            acc[0][0] += av.x * wv.x; acc[0][1] += av.x * wv.y; acc[0][2] += av.x * wv.z; acc[0][3] += av.x * wv.w;
            acc[1][0] += av.y * wv.x; acc[1][1] += av.y * wv.y; acc[1][2] += av.y * wv.z; acc[1][3] += av.y * wv.w;
            acc[2][0] += av.z * wv.x; acc[2][1] += av.z * wv.y; acc[2][2] += av.z * wv.z; acc[2][3] += av.z * wv.w;
            acc[3][0] += av.w * wv.x; acc[3][1] += av.w * wv.y; acc[3][2] += av.w * wv.z; acc[3][3] += av.w * wv.w;
        }
    }
    float4 bv = make_float4(0.f, 0.f, 0.f, 0.f);
    if (bias) bv = *(const float4*)(bias + n0 + tn * 4);
#pragma unroll
    for (int i = 0; i < 4; ++i) {
        int m = m0 + tm * 4 + i;
        float4 v;
        v.x = scale * acc[i][0] + bv.x;
        v.y = scale * acc[i][1] + bv.y;
        v.z = scale * acc[i][2] + bv.z;
        v.w = scale * acc[i][3] + bv.w;
        if (do_relu) {
            v.x = fmaxf(v.x, 0.f); v.y = fmaxf(v.y, 0.f);
            v.z = fmaxf(v.z, 0.f); v.w = fmaxf(v.w, 0.f);
        }
        *(float4*)(C + (size_t)m * N + n0 + tn * 4) = v;
    }
}

// ---------------------------------------------------------------------------
// pairwise: out[i][j][:] = log_softmax( sum_c relu(ur'[i][c]+ul[j][c]) * woutT[c][:] + bout )
// Stride 132 + row remap -> <=2-way conflicts (R7 fix).
// ---------------------------------------------------------------------------
__global__ __launch_bounds__(256) void pairwise_kernel(
    const float* __restrict__ u,      // [768][1024]
    const float* __restrict__ woutT,  // [1024][2]
    const float* __restrict__ bout,   // [2]
    float* __restrict__ out)          // [384][384][2]
{
    __shared__ float Ur[32][132];
    __shared__ float Ul[32][132];
    __shared__ float Wo[256];
    const int tid = threadIdx.x;
    const int j0 = blockIdx.x * 32, i0 = blockIdx.y * 32;
    const int ii = tid >> 4, jj = tid & 15;
    const int il0 = ii, il1 = ii + 16;
    const int jl0 = jj, jl1 = jj + 16;
    float acc000 = 0.f, acc001 = 0.f, acc010 = 0.f, acc011 = 0.f;
    float acc100 = 0.f, acc101 = 0.f, acc110 = 0.f, acc111 = 0.f;
    const int lrw = tid >> 3;
    const int lcb = (tid & 7) * 16;

    for (int cc = 0; cc < 1024; cc += 128) {
        __syncthreads();
#pragma unroll
        for (int q = 0; q < 4; ++q) {
            *(float4*)&Ur[lrw][lcb + 4 * q] =
                *(const float4*)(u + (size_t)(i0 + lrw) * 1024 + cc + lcb + 4 * q);
            *(float4*)&Ul[lrw][lcb + 4 * q] =
                *(const float4*)(u + (size_t)(384 + j0 + lrw) * 1024 + cc + lcb + 4 * q);
        }
        if (tid < 128)
            *(float2*)&Wo[tid * 2] = *(const float2*)(woutT + (size_t)(cc + tid) * 2);
        __syncthreads();

        for (int c = 0; c < 128; c += 4) {
            float4 a0  = *(const float4*)&Ur[il0][c];
            float4 a1  = *(const float4*)&Ur[il1][c];
            float4 b0v = *(const float4*)&Ul[jl0][c];
            float4 b1v = *(const float4*)&Ul[jl1][c];
            float4 wA4 = *(const float4*)&Wo[c * 2];
            float4 wB4 = *(const float4*)&Wo[c * 2 + 4];
#define PW_STEP(AX, W0, W1)                                   \
            { float rr;                                       \
              rr = fmaxf(a0.AX + b0v.AX, 0.f); acc000 += rr*(W0); acc001 += rr*(W1); \
              rr = fmaxf(a0.AX + b1v.AX, 0.f); acc010 += rr*(W0); acc011 += rr*(W1); \
              rr = fmaxf(a1.AX + b0v.AX, 0.f); acc100 += rr*(W0); acc101 += rr*(W1); \
              rr = fmaxf(a1.AX + b1v.AX, 0.f); acc110 += rr*(W0); acc111 += rr*(W1); }
            PW_STEP(x, wA4.x, wA4.y)
            PW_STEP(y, wA4.z, wA4.w)
            PW_STEP(z, wB4.x, wB4.y)
            PW_STEP(w, wB4.z, wB4.w)
#undef PW_STEP
        }
    }
    float2 bo = *(const float2*)bout;
    float pa[2][2][2] = {{{acc000, acc001}, {acc010, acc011}},
                         {{acc100, acc101}, {acc110, acc111}}};
#pragma unroll
    for (int pi = 0; pi < 2; ++pi)
#pragma unroll
        for (int pj = 0; pj < 2; ++pj) {
            float l0 = pa[pi][pj][0] + bo.x;
            float l1 = pa[pi][pj][1] + bo.y;
            float m = fmaxf(l0, l1);
            float lse = m + logf(expf(l0 - m) + expf(l1 - m));
            int ig = i0 + ii + 16 * pi;
            int jg = j0 + jj + 16 * pj;
            float2 o2; o2.x = l0 - lse; o2.y = l1 - lse;
            *(float2*)(out + ((size_t)ig * 384 + jg) * 2) = o2;
        }
}

// ---------------------------------------------------------------------------
extern "C" void kernel_launch(void* const* d_in, const int* in_sizes, int n_in,
                              void* d_out, int out_size, void* d_ws, size_t ws_size,
                              hipStream_t stream)
{
    const float* v_r  = (const float*)d_in[0];
    const float* v_l  = (const float*)d_in[1];
    const float* Wih0 = (const float*)d_in[2];
    const float* Whh0 = (const float*)d_in[3];
    const float* bih0 = (const float*)d_in[4];
    const float* bhh0 = (const float*)d_in[5];
    const float* Wih1 = (const float*)d_in[6];
    const float* Whh1 = (const float*)d_in[7];
    const float* bih1 = (const float*)d_in[8];
    const float* bhh1 = (const float*)d_in[9];
    const float* W1   = (const float*)d_in[10];
    const float* b1   = (const float*)d_in[11];
    const float* W2   = (const float*)d_in[12];
    const float* b2   = (const float*)d_in[13];
    const float* W3   = (const float*)d_in[14];
    const float* b3   = (const float*)d_in[15];
    const float* Wout = (const float*)d_in[16];
    const float* bout = (const float*)d_in[17];
    float* out = (float*)d_out;

    float* ws = (float*)d_ws;
    size_t off = 0;
    float* b0sum = ws + off; off += 2048;
    float* b1sum = ws + off; off += 2048;
    float* W3sum = ws + off; off += 1024 * 512;
    float* woutT = ws + off; off += 2048;
    float* pre0  = ws + off; off += (size_t)4 * 384 * 1024;
    float* out0  = ws + off; off += (size_t)2 * 384 * 512;
    float* pre1  = ws + off; off += (size_t)768 * 2048;
    float* out1  = ws + off; off += (size_t)2 * 384 * 512;
    float* h1    = ws + off; off += (size_t)768 * 1024;
    float* h2    = ws + off; off += (size_t)768 * 512;
    float* u     = ws + off; off += (size_t)768 * 1024;
    unsigned long long* pub0 = (unsigned long long*)(ws + off); off += 4 * 2 * 128 * 2;
    unsigned long long* pub1 = (unsigned long long*)(ws + off); off += 4 * 2 * 128 * 2;

    prep_kernel<<<512, 256, 0, stream>>>(bih0, bhh0, bih1, bhh1, W3, Wout,
                                         b0sum, b1sum, W3sum, woutT);
    proj0_kernel<<<dim3(384, 4), 256, 0, stream>>>(v_r, v_l, Wih0, b0sum, pre0);
    lstm_rec_kernel<<<64, 512, 0, stream>>>(Whh0, pre0, out0, pub0, 0);
    gemm_nt_kernel<<<dim3(2048 / 64, 768 / 64), 256, 0, stream>>>(
        out0, Wih1, b1sum, pre1, 768, 2048, 512, 1.f, 0);
    lstm_rec_kernel<<<64, 512, 0, stream>>>(Whh1, pre1, out1, pub1, 1);
    gemm_nt_kernel<<<dim3(1024 / 64, 768 / 64), 256, 0, stream>>>(
        out1, W1, b1, h1, 768, 1024, 512, 1.f, 1);
    gemm_nt_kernel<<<dim3(512 / 64, 768 / 64), 256, 0, stream>>>(
        h1, W2, b2, h2, 768, 512, 1024, 1.f, 1);
    gemm_nt_kernel<<<dim3(1024 / 64, 384 / 64), 256, 0, stream>>>(
        h2, W3sum, b3, u, 384, 1024, 512, 0.5f, 0);
    gemm_nt_kernel<<<dim3(1024 / 64, 384 / 64), 256, 0, stream>>>(
        h2 + (size_t)384 * 512, W3sum, nullptr, u + (size_t)384 * 1024, 384, 1024, 512, 0.5f, 0);
    pairwise_kernel<<<dim3(12, 12), 256, 0, stream>>>(u, woutT, bout, out);
}